// Round 5
// baseline (298.759 us; speedup 1.0000x reference)
//
#include <hip/hip_runtime.h>
#include <math.h>

#define MASK_THR 0.53f
#define BT 32
#define MMBLK 256   // matmul-chain blocks (lowest blockIdx => resident from t=0)
#define SCBLK 1152  // scatter blocks

// ---- one 32x32 output tile, 2x2 register blocking (proven correct r2-r4) ----
__device__ __forceinline__ void mm_tile(const float* __restrict__ A,
                                        const float* __restrict__ B,
                                        float* __restrict__ C, int N, bool addI,
                                        int bid) {
    __shared__ float As[BT][BT + 1];
    __shared__ float Bs[BT][BT + 1];
    int tid = threadIdx.x;
    int NT = N / BT;
    int bx = bid % NT, by = bid / NT;
    int rowBase = by * BT, colBase = bx * BT;
    int tx = tid & 15, ty = tid >> 4;
    int lr = tid >> 3;
    int lc = (tid & 7) * 4;
    float a00 = 0, a01 = 0, a10 = 0, a11 = 0;
    for (int t = 0; t < N; t += BT) {
        float4 av = *(const float4*)&A[(size_t)(rowBase + lr) * N + t + lc];
        float4 bv = *(const float4*)&B[(size_t)(t + lr) * N + colBase + lc];
        if (addI) {
            int r = rowBase + lr, c = t + lc;
            if (r == c + 0) av.x += 1.0f;
            if (r == c + 1) av.y += 1.0f;
            if (r == c + 2) av.z += 1.0f;
            if (r == c + 3) av.w += 1.0f;
            int r2 = t + lr, c2 = colBase + lc;
            if (r2 == c2 + 0) bv.x += 1.0f;
            if (r2 == c2 + 1) bv.y += 1.0f;
            if (r2 == c2 + 2) bv.z += 1.0f;
            if (r2 == c2 + 3) bv.w += 1.0f;
        }
        As[lr][lc + 0] = av.x; As[lr][lc + 1] = av.y;
        As[lr][lc + 2] = av.z; As[lr][lc + 3] = av.w;
        Bs[lr][lc + 0] = bv.x; Bs[lr][lc + 1] = bv.y;
        Bs[lr][lc + 2] = bv.z; Bs[lr][lc + 3] = bv.w;
        __syncthreads();
#pragma unroll
        for (int k = 0; k < BT; ++k) {
            float a0 = As[ty * 2][k], a1 = As[ty * 2 + 1][k];
            float b0 = Bs[k][tx * 2], b1 = Bs[k][tx * 2 + 1];
            a00 += a0 * b0; a01 += a0 * b1;
            a10 += a1 * b0; a11 += a1 * b1;
        }
        __syncthreads();
    }
    int r0 = rowBase + ty * 2, c0 = colBase + tx * 2;
    C[(size_t)r0 * N + c0] = a00;
    C[(size_t)r0 * N + c0 + 1] = a01;
    C[(size_t)(r0 + 1) * N + c0] = a10;
    C[(size_t)(r0 + 1) * N + c0 + 1] = a11;
}

// Chain barrier among the MMBLK blocks only.
// __syncthreads drains all waves' stores to L2 (vmcnt(0) before s_barrier);
// __threadfence flushes to the device coherence point; relaxed atomicAdd after
// the fence = release. Spin uses agent-scope acquire loads (invalidate caches).
__device__ __forceinline__ void chain_sync(unsigned* c) {
    __syncthreads();
    __threadfence();
    if (threadIdx.x == 0) {
        atomicAdd(c, 1u);
        while (__hip_atomic_load(c, __ATOMIC_ACQUIRE, __HIP_MEMORY_SCOPE_AGENT)
               < (unsigned)MMBLK)
            __builtin_amdgcn_s_sleep(8);
    }
    __syncthreads();
}

// Mega-kernel: blocks [0,MMBLK) run the whole CC chain (M^2,M^4,M^8,M^10,
// remap) flag-synced among themselves; blocks [MMBLK, MMBLK+SCBLK) do the
// whole priority scatter concurrently (they depend on nothing and nothing
// in this kernel depends on them; finalize is the next launch).
// Scatter packing: p in [0.53,1) => exponent fixed 126, mantissa orders as p;
// output needs only the winner's instance n => pack (mant<<9)|(NB1-n);
// atomicMax = max p, tie -> min n. Stale pre-read filter is monotone-safe.
__global__ __launch_bounds__(256) void k_mega(
        const float* __restrict__ adj, float* __restrict__ b0,
        float* __restrict__ b1, float* __restrict__ b2,
        float* __restrict__ rmap, unsigned* __restrict__ cnt, int N,
        const float* __restrict__ prob, const int* __restrict__ coords,
        unsigned* __restrict__ packed, int NE, int HW, int NB1,
        const int* __restrict__ d_size1) {
    int tid = threadIdx.x;
    if ((int)blockIdx.x < MMBLK) {
        int bid = blockIdx.x;
        mm_tile(adj, adj, b0, N, true, bid);   // M^2  = (A+I)^2
        chain_sync(&cnt[0]);
        mm_tile(b0, b0, b1, N, false, bid);    // M^4
        chain_sync(&cnt[1]);
        mm_tile(b1, b1, b2, N, false, bid);    // M^8
        chain_sync(&cnt[2]);
        mm_tile(b2, b0, b1, N, false, bid);    // M^10 = M^8 * M^2
        chain_sync(&cnt[3]);
        // remap[j] = 1 + max({j} U {i != j : M10[i][j] > 1}); classification
        // symmetric (symmetric adjacency; >1 test exact in fp32) => read ROW j.
        int wave = bid * 4 + (tid >> 6);
        int lane = tid & 63;
        if (wave < N) {
            const float* row = b1 + (size_t)wave * N;
            int best = wave;
            for (int i = lane; i < N; i += 64)
                if (i != wave && row[i] > 1.0f && i > best) best = i;
            for (int off = 32; off; off >>= 1) {
                int o = __shfl_down(best, off);
                if (o > best) best = o;
            }
            if (lane == 0) rmap[wave] = (float)(best + 1);
        }
        return;
    }
    // ---- scatter ----
    int sb = blockIdx.x - MMBLK;
    int size1 = *d_size1;
    int NE4 = NE >> 2;
    int stride = SCBLK * 256;
    for (int i4 = sb * 256 + tid; i4 < NE4; i4 += stride) {
        float4 p = ((const float4*)prob)[i4];
        int4 x = ((const int4*)coords)[i4];
        int4 y = ((const int4*)(coords + NE))[i4];
        int base = i4 * 4;
        float pv[4] = {p.x, p.y, p.z, p.w};
        int   xv[4] = {x.x, x.y, x.z, x.w};
        int   yv[4] = {y.x, y.y, y.z, y.w};
#pragma unroll
        for (int e = 0; e < 4; ++e) {
            if (pv[e] >= MASK_THR) {
                unsigned n = (unsigned)(base + e) / (unsigned)HW;
                unsigned v = ((__float_as_uint(pv[e]) & 0x7FFFFFu) << 9) |
                             (unsigned)(NB1 - (int)n);
                unsigned* addr = &packed[xv[e] * size1 + yv[e]];
                if (*addr < v) atomicMax(addr, v);
            }
        }
    }
}

__global__ void k_finalize(const unsigned* __restrict__ packed,
                           const float* __restrict__ rmap,
                           float* __restrict__ out, int total, int NB1) {
    int i4 = blockIdx.x * blockDim.x + threadIdx.x;
    if (i4 * 4 >= total) return;
    uint4 v = ((const uint4*)packed)[i4];
    float4 o;
    o.x = v.x ? rmap[NB1 - (int)(v.x & 0x1FFu)] : 0.0f;
    o.y = v.y ? rmap[NB1 - (int)(v.y & 0x1FFu)] : 0.0f;
    o.z = v.z ? rmap[NB1 - (int)(v.z & 0x1FFu)] : 0.0f;
    o.w = v.w ? rmap[NB1 - (int)(v.w & 0x1FFu)] : 0.0f;
    ((float4*)out)[i4] = o;
}

extern "C" void kernel_launch(void* const* d_in, const int* in_sizes, int n_in,
                              void* d_out, int out_size, void* d_ws, size_t ws_size,
                              hipStream_t stream) {
    const float* prob   = (const float*)d_in[0];
    const int*   coords = (const int*)d_in[1];
    const float* adj    = (const float*)d_in[2];
    const int*   dsz1   = (const int*)d_in[4];

    const int NE = in_sizes[0];            // N*h*w = 4718592
    const int NN = in_sizes[2];            // N*N
    int N = (int)(sqrt((double)NN) + 0.5); // 512
    const int HW = NE / N;                 // 9216
    const int total = out_size;            // 1048576
    const int NB1 = N - 1;

    char* ws = (char*)d_ws;
    unsigned* packed = (unsigned*)ws;
    size_t off = (size_t)total * 4;
    unsigned* cnt = (unsigned*)(ws + off); off += 256;   // 4 counters, padded
    float* b0 = (float*)(ws + off); off += (size_t)NN * 4;
    float* b1 = (float*)(ws + off); off += (size_t)NN * 4;
    float* b2 = (float*)(ws + off); off += (size_t)NN * 4;
    float* rmap = (float*)(ws + off);

    // zero packed + counters in one memset
    hipMemsetAsync(packed, 0, (size_t)total * 4 + 256, stream);

    void* unused = nullptr; (void)unused; (void)ws_size; (void)n_in;

    dim3 grid(MMBLK + SCBLK);
    hipLaunchKernelGGL(k_mega, grid, dim3(256), 0, stream,
                       adj, b0, b1, b2, rmap, cnt, N,
                       prob, coords, packed, NE, HW, NB1, dsz1);

    k_finalize<<<(total / 4 + 255) / 256, 256, 0, stream>>>(packed, rmap,
                                                            (float*)d_out,
                                                            total, NB1);
}

// Round 6
// 175.996 us; speedup vs baseline: 1.6975x; 1.6975x over previous
//
#include <hip/hip_runtime.h>
#include <math.h>

#define MASK_THR 0.53f
#define BT 32

// ---- Stage 1: priority scatter, 32-bit packed atomics, sector-spread. ----
// p in [0.53,1) => exponent fixed at 126 => 23 mantissa bits order as p.
// Output needs only the winner's instance n => pack (mant<<9)|(NB1-n):
// atomicMax = max p, tie -> min n (== n of min flat index since flat = n*HW+i).
// Bin b lives at packed[b << S] (S dwords shift) to spread atomics across
// 32B sectors (memory-side RMW appears sector-granular: WRITE ~31B/op).
__global__ __launch_bounds__(256) void k_scatter(
        const float* __restrict__ prob, const int* __restrict__ coords,
        unsigned* __restrict__ packed, int NE, int HW4, int NB1,
        const int* __restrict__ d_size1, int S) {
    int i4 = blockIdx.x * blockDim.x + threadIdx.x;
    if (i4 * 4 >= NE) return;
    int size1 = *d_size1;
    float4 p = ((const float4*)prob)[i4];
    int4 x = ((const int4*)coords)[i4];
    int4 y = ((const int4*)(coords + NE))[i4];
    // HW % 4 == 0, so all 4 pixels of this thread share instance n.
    unsigned n = (unsigned)i4 / (unsigned)HW4;
    unsigned tie = (unsigned)(NB1 - (int)n);
    float pv[4] = {p.x, p.y, p.z, p.w};
    int   xv[4] = {x.x, x.y, x.z, x.w};
    int   yv[4] = {y.x, y.y, y.z, y.w};
#pragma unroll
    for (int e = 0; e < 4; ++e) {
        if (pv[e] >= MASK_THR) {
            unsigned v = ((__float_as_uint(pv[e]) & 0x7FFFFFu) << 9) | tie;
            atomicMax(&packed[(size_t)(xv[e] * size1 + yv[e]) << S], v);
        }
    }
}

// ---- Stage 2: matmul, 32x32 tile, 2x2/thread, optional pair-summed inputs
// (A = A0 + A1 elementwise, exact: integer-valued fp32 < 2^24), optional +I
// on both operands, split-K: blockIdx.x / nTiles selects K-half and output
// partial buffer. All values exact integers => >1 classification exact. ----
__global__ __launch_bounds__(256) void k_mm(
        const float* __restrict__ A0, const float* __restrict__ A1,
        const float* __restrict__ B0, const float* __restrict__ B1,
        float* __restrict__ Cp, float* __restrict__ Cq,
        int N, int addI, int kLen) {
    __shared__ float As[BT][BT + 1];
    __shared__ float Bs[BT][BT + 1];
    int NT = N / BT;
    int nTiles = NT * NT;
    int bid = blockIdx.x % nTiles;
    int sp  = blockIdx.x / nTiles;
    int kBase = sp * kLen;
    float* C = sp ? Cq : Cp;
    int tid = threadIdx.x;
    int bx = bid % NT, by = bid / NT;
    int rowBase = by * BT, colBase = bx * BT;
    int tx = tid & 15, ty = tid >> 4;
    int lr = tid >> 3;
    int lc = (tid & 7) * 4;
    float a00 = 0, a01 = 0, a10 = 0, a11 = 0;
    for (int t = kBase; t < kBase + kLen; t += BT) {
        size_t ai = (size_t)(rowBase + lr) * N + t + lc;
        size_t bi = (size_t)(t + lr) * N + colBase + lc;
        float4 av = *(const float4*)(A0 + ai);
        float4 bv = *(const float4*)(B0 + bi);
        if (A1) { float4 w = *(const float4*)(A1 + ai);
                  av.x += w.x; av.y += w.y; av.z += w.z; av.w += w.w; }
        if (B1) { float4 w = *(const float4*)(B1 + bi);
                  bv.x += w.x; bv.y += w.y; bv.z += w.z; bv.w += w.w; }
        if (addI) {
            int r = rowBase + lr, c = t + lc;
            if (r == c + 0) av.x += 1.0f;
            if (r == c + 1) av.y += 1.0f;
            if (r == c + 2) av.z += 1.0f;
            if (r == c + 3) av.w += 1.0f;
            int r2 = t + lr, c2 = colBase + lc;
            if (r2 == c2 + 0) bv.x += 1.0f;
            if (r2 == c2 + 1) bv.y += 1.0f;
            if (r2 == c2 + 2) bv.z += 1.0f;
            if (r2 == c2 + 3) bv.w += 1.0f;
        }
        As[lr][lc + 0] = av.x; As[lr][lc + 1] = av.y;
        As[lr][lc + 2] = av.z; As[lr][lc + 3] = av.w;
        Bs[lr][lc + 0] = bv.x; Bs[lr][lc + 1] = bv.y;
        Bs[lr][lc + 2] = bv.z; Bs[lr][lc + 3] = bv.w;
        __syncthreads();
#pragma unroll
        for (int k = 0; k < BT; ++k) {
            float a0 = As[ty * 2][k], a1 = As[ty * 2 + 1][k];
            float b0 = Bs[k][tx * 2], b1 = Bs[k][tx * 2 + 1];
            a00 += a0 * b0; a01 += a0 * b1;
            a10 += a1 * b0; a11 += a1 * b1;
        }
        __syncthreads();
    }
    int r0 = rowBase + ty * 2, c0 = colBase + tx * 2;
    C[(size_t)r0 * N + c0] = a00;
    C[(size_t)r0 * N + c0 + 1] = a01;
    C[(size_t)(r0 + 1) * N + c0] = a10;
    C[(size_t)(r0 + 1) * N + c0 + 1] = a11;
}

// remap[j] = 1 + max({j} U {i != j : M10[i][j] > 1}); classification symmetric
// (symmetric adjacency => symmetric counts; test exact in fp32) => read ROW j.
__global__ void k_remap(const float* __restrict__ R0, const float* __restrict__ R1,
                        float* __restrict__ rmap, int N) {
    int j = blockIdx.x;
    int lane = threadIdx.x;  // 64
    const float* r0 = R0 + (size_t)j * N;
    const float* r1 = R1 ? R1 + (size_t)j * N : nullptr;
    int best = j;
    for (int i = lane; i < N; i += 64) {
        float v = r0[i] + (r1 ? r1[i] : 0.0f);
        if (i != j && v > 1.0f && i > best) best = i;
    }
    for (int off = 32; off; off >>= 1) {
        int o = __shfl_down(best, off);
        if (o > best) best = o;
    }
    if (lane == 0) rmap[j] = (float)(best + 1);
}

__global__ void k_finalize(const unsigned* __restrict__ packed,
                           const float* __restrict__ rmap,
                           float* __restrict__ out, int total, int NB1, int S) {
    int i4 = blockIdx.x * blockDim.x + threadIdx.x;
    if (i4 * 4 >= total) return;
    unsigned v[4];
    if (S == 0) {
        uint4 u = ((const uint4*)packed)[i4];
        v[0] = u.x; v[1] = u.y; v[2] = u.z; v[3] = u.w;
    } else {
#pragma unroll
        for (int e = 0; e < 4; ++e)
            v[e] = packed[(size_t)(i4 * 4 + e) << S];
    }
    float o[4];
#pragma unroll
    for (int e = 0; e < 4; ++e)
        o[e] = v[e] ? rmap[NB1 - (int)(v[e] & 0x1FFu)] : 0.0f;
    ((float4*)out)[i4] = make_float4(o[0], o[1], o[2], o[3]);
}

extern "C" void kernel_launch(void* const* d_in, const int* in_sizes, int n_in,
                              void* d_out, int out_size, void* d_ws, size_t ws_size,
                              hipStream_t stream) {
    const float* prob   = (const float*)d_in[0];
    const int*   coords = (const int*)d_in[1];
    const float* adj    = (const float*)d_in[2];
    const int*   dsz1   = (const int*)d_in[4];

    const int NE = in_sizes[0];            // N*h*w = 4718592
    const int NN = in_sizes[2];            // N*N
    int N = (int)(sqrt((double)NN) + 0.5); // 512
    const int HW = NE / N;                 // 9216
    const int total = out_size;            // 1048576
    const int NB1 = N - 1;

    // choose packed stride (S dwords-shift) and split-K by ws budget
    const size_t bufB = (size_t)NN * 4;    // 1 MB
    int S = -1; bool split = true;
    for (int s = 3; s >= 0 && S < 0; --s)
        if ((((size_t)total * 4) << s) + bufB * 8 + 4096 <= ws_size) S = s;
    if (S < 0) {
        split = false;
        for (int s = 3; s >= 0 && S < 0; --s)
            if ((((size_t)total * 4) << s) + bufB * 4 + 4096 <= ws_size) S = s;
        if (S < 0) S = 0;
    }

    char* ws = (char*)d_ws;
    unsigned* packed = (unsigned*)ws;
    size_t off = ((size_t)total * 4) << S;
    float* p0 = (float*)(ws + off); off += bufB;
    float* p1 = (float*)(ws + off); off += bufB;
    float* p2 = (float*)(ws + off); off += bufB;
    float* p3 = (float*)(ws + off); off += bufB;
    float *q0 = nullptr, *q1 = nullptr, *q2 = nullptr, *q3 = nullptr;
    if (split) {
        q0 = (float*)(ws + off); off += bufB;
        q1 = (float*)(ws + off); off += bufB;
        q2 = (float*)(ws + off); off += bufB;
        q3 = (float*)(ws + off); off += bufB;
    }
    float* rmap = (float*)(ws + off);

    hipMemsetAsync(packed, 0, ((size_t)total * 4) << S, stream);

    k_scatter<<<(NE / 4 + 255) / 256, 256, 0, stream>>>(
        prob, coords, packed, NE, HW / 4, NB1, dsz1, S);

    const int nTiles = (N / BT) * (N / BT);   // 256
    const int nsplit = split ? 2 : 1;
    const int kLen = N / nsplit;
    dim3 mg(nTiles * nsplit);
    // M^2 = (A+I)^2
    k_mm<<<mg, 256, 0, stream>>>(adj, nullptr, adj, nullptr, p0, q0, N, 1, kLen);
    // M^4 = M^2 * M^2
    k_mm<<<mg, 256, 0, stream>>>(p0, q0, p0, q0, p1, q1, N, 0, kLen);
    // M^8 = M^4 * M^4
    k_mm<<<mg, 256, 0, stream>>>(p1, q1, p1, q1, p2, q2, N, 0, kLen);
    // M^10 = M^8 * M^2
    k_mm<<<mg, 256, 0, stream>>>(p2, q2, p0, q0, p3, q3, N, 0, kLen);

    k_remap<<<N, 64, 0, stream>>>(p3, q3, rmap, N);

    k_finalize<<<(total / 4 + 255) / 256, 256, 0, stream>>>(
        packed, rmap, (float*)d_out, total, NB1, S);
}